// Round 2
// baseline (2651.792 us; speedup 1.0000x reference)
//
#include <hip/hip_runtime.h>
#include <hip/hip_bf16.h>
#include <stdint.h>

// MoE top-2, E=16, H=4096, INTER=448, tokens = 8192.
// Strategy: router (fp64 logits) -> expert-grouped rows via atomic perm lists ->
// grouped fp16 MFMA GEMM (gate+up fused as 896-wide N) -> swiglu+route-weight ->
// grouped fp16 MFMA down GEMM with fp32 atomicAdd scatter into out.
// R1: m97-pattern staging (global_load_lds dwordx4, linear LDS, BK=32).
// R2: gate/up GEMM was GRID-limited (896 jobs = 3.5 blocks/CU, Occupancy 37%,
//     MfmaUtil 14%). K-split by 2 -> 1792 jobs (~7 blocks/CU, all co-resident,
//     no tail). Partials accumulate fp32 via atomicAdd into gu32; swiglu reads
//     fp32. d16 aliases wgu (dead after gate/up GEMM) to keep ws <= 288 MB.

#define NE    16
#define INTER 448
#define HDIM  4096
#define BS    8192
#define ROWS  (BS * 2)
#define NGU   896       // gate(448) + up(448) per expert
#define CAP   8192      // perm capacity per expert (worst case)

typedef __attribute__((ext_vector_type(8))) _Float16 half8;
typedef __attribute__((ext_vector_type(4))) _Float16 half4;
typedef __attribute__((ext_vector_type(4))) float    f32x4;

// async 16B global->LDS. LDS dest must be wave-uniform base (+ lane*16 implicit);
// global src is per-lane (gather-friendly).
__device__ __forceinline__ void gld16(const _Float16* g, _Float16* l) {
    __builtin_amdgcn_global_load_lds(
        (const __attribute__((address_space(1))) void*)g,
        (__attribute__((address_space(3))) void*)l, 16, 0, 0);
}

// ---------------- converters: fp32 -> fp16 ----------------

// g/u [7168,4096] -> wgu fp16 [E][896][4096]; col_off=0 for gate rows, 448 for up rows
__global__ __launch_bounds__(256) void k_convert_gu(const float* __restrict__ src,
                                                    _Float16* __restrict__ dst,
                                                    int col_off) {
    int64_t id  = (int64_t)blockIdx.x * 256 + threadIdx.x;   // 7168*4096/8 threads
    int64_t k   = (id & 511) * 8;
    int64_t row = id >> 9;                                   // 0..7167
    int     e   = (int)(row / 448);
    int64_t drow = (int64_t)e * NGU + col_off + (row - (int64_t)e * 448);
    const float4* s = reinterpret_cast<const float4*>(src + row * HDIM + k);
    float4 a = s[0], b = s[1];
    half8 o;
    o[0] = (_Float16)a.x; o[1] = (_Float16)a.y; o[2] = (_Float16)a.z; o[3] = (_Float16)a.w;
    o[4] = (_Float16)b.x; o[5] = (_Float16)b.y; o[6] = (_Float16)b.z; o[7] = (_Float16)b.w;
    *reinterpret_cast<half8*>(dst + drow * HDIM + k) = o;
}

// d [4096,7168] -> fp16 same layout
__global__ __launch_bounds__(256) void k_convert_flat(const float* __restrict__ src,
                                                      _Float16* __restrict__ dst) {
    int64_t id = ((int64_t)blockIdx.x * 256 + threadIdx.x) * 8;
    const float4* s = reinterpret_cast<const float4*>(src + id);
    float4 a = s[0], b = s[1];
    half8 o;
    o[0] = (_Float16)a.x; o[1] = (_Float16)a.y; o[2] = (_Float16)a.z; o[3] = (_Float16)a.w;
    o[4] = (_Float16)b.x; o[5] = (_Float16)b.y; o[6] = (_Float16)b.z; o[7] = (_Float16)b.w;
    *reinterpret_cast<half8*>(dst + id) = o;
}

// ---------------- router: one wave per token ----------------
__global__ __launch_bounds__(64) void k_router(const float* __restrict__ x,
                                               const float* __restrict__ gw,
                                               _Float16* __restrict__ xh,
                                               int* __restrict__ counts,
                                               int* __restrict__ perm,
                                               float* __restrict__ rw) {
    int t = blockIdx.x;
    int lane = threadIdx.x;
    const float* xr = x + (int64_t)t * HDIM;
    double acc[NE];
#pragma unroll
    for (int e = 0; e < NE; e++) acc[e] = 0.0;
    for (int h = lane * 4; h < HDIM; h += 256) {
        float4 xv = *reinterpret_cast<const float4*>(xr + h);
        half4 o;
        o[0] = (_Float16)xv.x; o[1] = (_Float16)xv.y;
        o[2] = (_Float16)xv.z; o[3] = (_Float16)xv.w;
        *reinterpret_cast<half4*>(xh + (int64_t)t * HDIM + h) = o;
#pragma unroll
        for (int e = 0; e < NE; e++) {
            float4 gv = *reinterpret_cast<const float4*>(gw + e * HDIM + h);
            acc[e] += (double)xv.x * gv.x + (double)xv.y * gv.y
                    + (double)xv.z * gv.z + (double)xv.w * gv.w;
        }
    }
#pragma unroll
    for (int e = 0; e < NE; e++) {
#pragma unroll
        for (int off = 32; off > 0; off >>= 1)
            acc[e] += __shfl_xor(acc[e], off, 64);
    }
    if (lane == 0) {
        int i0 = 0; double l0 = acc[0];
        for (int e = 1; e < NE; e++) if (acc[e] > l0) { l0 = acc[e]; i0 = e; }
        double l1 = -1e300; int i1 = 0;
        for (int e = 0; e < NE; e++) if (e != i0 && acc[e] > l1) { l1 = acc[e]; i1 = e; }
        float w0 = 1.0f / (1.0f + __expf((float)(l1 - l0)));
        float w1 = 1.0f - w0;
        int p0 = atomicAdd(&counts[i0], 1);
        int p1 = atomicAdd(&counts[i1], 1);
        perm[i0 * CAP + p0] = t * 2;
        perm[i1 * CAP + p1] = t * 2 + 1;
        rw[t * 2]     = w0;
        rw[t * 2 + 1] = w1;
    }
}

// ---------------- grouped GEMM, 128x128 tile, BK=32, fp16 MFMA 16x16x32 ----------------
// m97 structure: global_load_lds staging into linear LDS, 2 barriers per K-step.
// KSPLIT blocks per tile split the K range; partials accumulate via fp32 atomicAdd.
// DOWN=false: A = xh[token][HDIM] gathered, B = wgu[e][896][HDIM], C -> atomicAdd gu32
// DOWN=true : A = h[row][448] gathered,    B = d16[hdim][7168] (e-slice), C -> atomicAdd out
template <int KTOT, int KSPLIT, bool DOWN>
__global__ __launch_bounds__(256, 6) void k_gemm(const _Float16* __restrict__ A,
                                                 const _Float16* __restrict__ B,
                                                 const int* __restrict__ counts,
                                                 const int* __restrict__ perm,
                                                 float* __restrict__ gu32,
                                                 float* __restrict__ out) {
    int e  = blockIdx.z & (NE - 1);
    int ks = blockIdx.z >> 4;                 // which K-split slice
    int nt = blockIdx.x;
    int cnt = counts[e];
    const int KLEN = KTOT / KSPLIT;
    const int k0   = ks * KLEN;
    __shared__ __align__(16) _Float16 As[128 * 32];   // linear: gld_lds needs contiguous dest
    __shared__ __align__(16) _Float16 Bs[128 * 32];
    __shared__ int perm_s[128];
    int tid  = threadIdx.x;
    int lane = tid & 63, wave = tid >> 6;
    int wm = wave >> 1, wn = wave & 1;        // 2x2 waves, each 64x64
    int lm = lane & 15, lq = lane >> 4;

    // staging geometry: wave w covers rows [w*16, +16) and [64+w*16, +16)
    // lane l -> row offset l>>2, 16B chunk (l&3) within the 64B row
    int rrow = lane >> 2;
    int cseg = (lane & 3) * 8;                // halves
    int row0 = wave * 16 + rrow;              // rows 0..63
    int row1 = 64 + wave * 16 + rrow;         // rows 64..127
    _Float16* As0 = &As[(wave * 16) * 32];    // wave-uniform LDS bases
    _Float16* As1 = &As[(64 + wave * 16) * 32];
    _Float16* Bs0 = &Bs[(wave * 16) * 32];
    _Float16* Bs1 = &Bs[(64 + wave * 16) * 32];

    // B row pointers depend only on (e, nt, ks) — hoist out of the mt loop
    const _Float16 *b0, *b1;
    if (DOWN) {
        b0 = B + (int64_t)(nt * 128 + row0) * (NE * INTER) + e * INTER + k0 + cseg;
        b1 = B + (int64_t)(nt * 128 + row1) * (NE * INTER) + e * INTER + k0 + cseg;
    } else {
        b0 = B + ((int64_t)e * NGU + nt * 128 + row0) * HDIM + k0 + cseg;
        b1 = B + ((int64_t)e * NGU + nt * 128 + row1) * HDIM + k0 + cseg;
    }

    for (int mt = blockIdx.y; mt * 128 < cnt; mt += gridDim.y) {
        __syncthreads();                      // protect perm_s vs previous epilogue
        if (tid < 128) {
            int r = mt * 128 + tid;
            perm_s[tid] = (r < cnt) ? perm[e * CAP + r] : -1;
        }
        __syncthreads();
        int pr0 = perm_s[row0], pr1 = perm_s[row1];
        const _Float16 *a0, *a1;
        if (DOWN) {
            a0 = A + (pr0 < 0 ? 0 : (int64_t)pr0 * INTER) + k0 + cseg;
            a1 = A + (pr1 < 0 ? 0 : (int64_t)pr1 * INTER) + k0 + cseg;
        } else {
            a0 = A + (pr0 < 0 ? 0 : (int64_t)(pr0 >> 1) * HDIM) + k0 + cseg;
            a1 = A + (pr1 < 0 ? 0 : (int64_t)(pr1 >> 1) * HDIM) + k0 + cseg;
        }
        const _Float16 *bb0 = b0, *bb1 = b1;

        f32x4 acc[4][4];
#pragma unroll
        for (int i = 0; i < 4; i++)
#pragma unroll
            for (int j = 0; j < 4; j++) acc[i][j] = (f32x4){0.f, 0.f, 0.f, 0.f};

#pragma unroll 1
        for (int kt = 0; kt < KLEN; kt += 32) {
            gld16(a0,  As0);  gld16(a1,  As1);
            gld16(bb0, Bs0);  gld16(bb1, Bs1);
            a0 += 32; a1 += 32; bb0 += 32; bb1 += 32;
            __syncthreads();                  // vmcnt(0) drain -> tiles resident
            half8 af[4], bfr[4];
#pragma unroll
            for (int mi = 0; mi < 4; mi++)
                af[mi] = *reinterpret_cast<const half8*>(&As[(wm * 64 + mi * 16 + lm) * 32 + lq * 8]);
#pragma unroll
            for (int ni = 0; ni < 4; ni++)
                bfr[ni] = *reinterpret_cast<const half8*>(&Bs[(wn * 64 + ni * 16 + lm) * 32 + lq * 8]);
#pragma unroll
            for (int mi = 0; mi < 4; mi++)
#pragma unroll
                for (int ni = 0; ni < 4; ni++)
                    acc[mi][ni] = __builtin_amdgcn_mfma_f32_16x16x32_f16(af[mi], bfr[ni], acc[mi][ni], 0, 0, 0);
            __syncthreads();                  // all reads done before next stage overwrites
        }
        // epilogue: C/D layout col=lane&15, row=(lane>>4)*4+reg  [m89/m91 verified]
#pragma unroll
        for (int mi = 0; mi < 4; mi++) {
#pragma unroll
            for (int r = 0; r < 4; r++) {
                int row = wm * 64 + mi * 16 + lq * 4 + r;
                int g = perm_s[row];
                if (g < 0) continue;
#pragma unroll
                for (int ni = 0; ni < 4; ni++) {
                    int col = nt * 128 + wn * 64 + ni * 16 + lm;
                    float v = acc[mi][ni][r];
                    if (DOWN) atomicAdd(&out[(int64_t)(g >> 1) * HDIM + col], v);
                    else      atomicAdd(&gu32[(int64_t)g * NGU + col], v);
                }
            }
        }
    }
}

// ---------------- swiglu + routing-weight fold (fp32 in, fp16 out) ----------------
__global__ __launch_bounds__(256) void k_swiglu(const float* __restrict__ gu,
                                                const float* __restrict__ rw,
                                                _Float16* __restrict__ h) {
    int64_t id  = (int64_t)blockIdx.x * 256 + threadIdx.x;   // ROWS*448/8 threads
    int64_t row = id / 56;
    int64_t j   = (id - row * 56) * 8;
    float w = rw[row];
    float4 g0 = *reinterpret_cast<const float4*>(gu + row * NGU + j);
    float4 g1 = *reinterpret_cast<const float4*>(gu + row * NGU + j + 4);
    float4 u0 = *reinterpret_cast<const float4*>(gu + row * NGU + 448 + j);
    float4 u1 = *reinterpret_cast<const float4*>(gu + row * NGU + 448 + j + 4);
    float gv[8] = {g0.x, g0.y, g0.z, g0.w, g1.x, g1.y, g1.z, g1.w};
    float uv[8] = {u0.x, u0.y, u0.z, u0.w, u1.x, u1.y, u1.z, u1.w};
    half8 o;
#pragma unroll
    for (int i = 0; i < 8; i++) {
        float g = gv[i];
        float s = g / (1.0f + __expf(-g));
        o[i] = (_Float16)(s * uv[i] * w);
    }
    *reinterpret_cast<half8*>(h + row * INTER + j) = o;
}

// ---------------- launch ----------------
extern "C" void kernel_launch(void* const* d_in, const int* in_sizes, int n_in,
                              void* d_out, int out_size, void* d_ws, size_t ws_size,
                              hipStream_t stream) {
    (void)in_sizes; (void)n_in; (void)ws_size;
    const float* hid    = (const float*)d_in[0];
    const float* gate_w = (const float*)d_in[1];
    const float* u      = (const float*)d_in[2];
    const float* g      = (const float*)d_in[3];
    const float* d      = (const float*)d_in[4];
    float* out = (float*)d_out;

    // ws layout (bytes): ~258.5 MB total. d16 ALIASES wgu (wgu dead after gate/up
    // GEMM; convert_flat runs after it in-stream).
    char* w = (char*)d_ws;
    _Float16* xh    = (_Float16*)(w);                 //  67,108,864  x fp16 [8192][4096]
    _Float16* wgu   = (_Float16*)(w + 67108864);      // 117,440,512  [16][896][4096]
    _Float16* d16   = (_Float16*)(w + 67108864);      //  58,720,256  [4096][7168] (alias)
    float*    gu32  = (float*)   (w + 184549376);     //  58,720,256  [16384][896] fp32
    _Float16* hbuf  = (_Float16*)(w + 243269632);     //  14,680,064  [16384][448]
    int*      perm  = (int*)     (w + 257949696);     //     524,288  [16][8192]
    float*    rw    = (float*)   (w + 258473984);     //      65,536  [16384]
    int*      cnts  = (int*)     (w + 258539520);     //          64

    hipMemsetAsync(d_out, 0, (size_t)out_size * sizeof(float), stream);
    hipMemsetAsync(gu32, 0, 58720256, stream);
    hipMemsetAsync(cnts, 0, 64, stream);

    k_convert_gu<<<14336, 256, 0, stream>>>(g, wgu, 0);      // gate rows -> cols [0,448)
    k_convert_gu<<<14336, 256, 0, stream>>>(u, wgu, 448);    // up rows   -> cols [448,896)
    k_router<<<BS, 64, 0, stream>>>(hid, gate_w, xh, cnts, perm, rw);
    // gate/up: K split 2 ways (z = e + 16*ks) -> 1792 work blocks, ~7/CU resident
    k_gemm<HDIM, 2, false><<<dim3(7, 16, 32), 256, 0, stream>>>(xh, wgu, cnts, perm, gu32, out);
    k_convert_flat<<<14336, 256, 0, stream>>>(d, d16);       // overwrites wgu (dead)
    k_swiglu<<<3584, 256, 0, stream>>>(gu32, rw, hbuf);
    k_gemm<INTER, 1, true><<<dim3(32, 16, NE), 256, 0, stream>>>(hbuf, d16, cnts, perm, gu32, out);
}

// Round 3
// 1169.611 us; speedup vs baseline: 2.2672x; 2.2672x over previous
//
#include <hip/hip_runtime.h>
#include <hip/hip_bf16.h>
#include <stdint.h>

// MoE top-2, E=16, H=4096, INTER=448, tokens = 8192.
// Strategy: router (fp64 logits) -> expert-grouped rows via atomic perm lists ->
// grouped fp16 MFMA GEMM (gate+up fused as 896-wide N) -> swiglu+route-weight ->
// grouped fp16 MFMA down GEMM, parity-split into store-pass + add-pass (NO atomics).
// R1: m97-pattern staging (global_load_lds dwordx4, linear LDS, BK=32). 368us gate/up.
// R2 (reverted): KSPLIT + fp32 atomicAdd partials -> cross-XCD line ping-pong,
//     ~128B HBM RMW per atomic lane-op, gate/up 1380us. Occupancy is reg-capped
//     at 4 blocks/CU (64 AGPR acc + ~60 VGPR), so KSPLIT's extra blocks were moot.
// R3: down GEMM de-atomized. Router builds 32 parity groups (expert x slot).
//     Down pass-even: plain stores to out (covers every token row exactly once,
//     so no out memset). Down pass-odd: non-atomic load-add-store, serialized by
//     stream order. Gate/up GEMM identical to R1.

#define NE    16
#define INTER 448
#define HDIM  4096
#define BS    8192
#define ROWS  (BS * 2)
#define NGU   896       // gate(448) + up(448) per expert
#define CAP   8192      // perm capacity per (group) list

typedef __attribute__((ext_vector_type(8))) _Float16 half8;
typedef __attribute__((ext_vector_type(4))) _Float16 half4;
typedef __attribute__((ext_vector_type(4))) float    f32x4;

// async 16B global->LDS. LDS dest must be wave-uniform base (+ lane*16 implicit);
// global src is per-lane (gather-friendly).
__device__ __forceinline__ void gld16(const _Float16* g, _Float16* l) {
    __builtin_amdgcn_global_load_lds(
        (const __attribute__((address_space(1))) void*)g,
        (__attribute__((address_space(3))) void*)l, 16, 0, 0);
}

// ---------------- converters: fp32 -> fp16 ----------------

// g/u [7168,4096] -> wgu fp16 [E][896][4096]; col_off=0 for gate rows, 448 for up rows
__global__ __launch_bounds__(256) void k_convert_gu(const float* __restrict__ src,
                                                    _Float16* __restrict__ dst,
                                                    int col_off) {
    int64_t id  = (int64_t)blockIdx.x * 256 + threadIdx.x;   // 7168*4096/8 threads
    int64_t k   = (id & 511) * 8;
    int64_t row = id >> 9;                                   // 0..7167
    int     e   = (int)(row / 448);
    int64_t drow = (int64_t)e * NGU + col_off + (row - (int64_t)e * 448);
    const float4* s = reinterpret_cast<const float4*>(src + row * HDIM + k);
    float4 a = s[0], b = s[1];
    half8 o;
    o[0] = (_Float16)a.x; o[1] = (_Float16)a.y; o[2] = (_Float16)a.z; o[3] = (_Float16)a.w;
    o[4] = (_Float16)b.x; o[5] = (_Float16)b.y; o[6] = (_Float16)b.z; o[7] = (_Float16)b.w;
    *reinterpret_cast<half8*>(dst + drow * HDIM + k) = o;
}

// d [4096,7168] -> fp16 same layout
__global__ __launch_bounds__(256) void k_convert_flat(const float* __restrict__ src,
                                                      _Float16* __restrict__ dst) {
    int64_t id = ((int64_t)blockIdx.x * 256 + threadIdx.x) * 8;
    const float4* s = reinterpret_cast<const float4*>(src + id);
    float4 a = s[0], b = s[1];
    half8 o;
    o[0] = (_Float16)a.x; o[1] = (_Float16)a.y; o[2] = (_Float16)a.z; o[3] = (_Float16)a.w;
    o[4] = (_Float16)b.x; o[5] = (_Float16)b.y; o[6] = (_Float16)b.z; o[7] = (_Float16)b.w;
    *reinterpret_cast<half8*>(dst + id) = o;
}

// ---------------- router: one wave per token ----------------
// counts[0..15]  : combined per-expert counts (gate/up GEMM)
// counts[16..47] : parity-group counts, gi = expert*2 + slot (down GEMM)
__global__ __launch_bounds__(64) void k_router(const float* __restrict__ x,
                                               const float* __restrict__ gw,
                                               _Float16* __restrict__ xh,
                                               int* __restrict__ counts,
                                               int* __restrict__ perm,   // [16][CAP] combined
                                               int* __restrict__ pperm,  // [32][CAP] parity
                                               float* __restrict__ rw) {
    int t = blockIdx.x;
    int lane = threadIdx.x;
    const float* xr = x + (int64_t)t * HDIM;
    double acc[NE];
#pragma unroll
    for (int e = 0; e < NE; e++) acc[e] = 0.0;
    for (int h = lane * 4; h < HDIM; h += 256) {
        float4 xv = *reinterpret_cast<const float4*>(xr + h);
        half4 o;
        o[0] = (_Float16)xv.x; o[1] = (_Float16)xv.y;
        o[2] = (_Float16)xv.z; o[3] = (_Float16)xv.w;
        *reinterpret_cast<half4*>(xh + (int64_t)t * HDIM + h) = o;
#pragma unroll
        for (int e = 0; e < NE; e++) {
            float4 gv = *reinterpret_cast<const float4*>(gw + e * HDIM + h);
            acc[e] += (double)xv.x * gv.x + (double)xv.y * gv.y
                    + (double)xv.z * gv.z + (double)xv.w * gv.w;
        }
    }
#pragma unroll
    for (int e = 0; e < NE; e++) {
#pragma unroll
        for (int off = 32; off > 0; off >>= 1)
            acc[e] += __shfl_xor(acc[e], off, 64);
    }
    if (lane == 0) {
        int i0 = 0; double l0 = acc[0];
        for (int e = 1; e < NE; e++) if (acc[e] > l0) { l0 = acc[e]; i0 = e; }
        double l1 = -1e300; int i1 = 0;
        for (int e = 0; e < NE; e++) if (e != i0 && acc[e] > l1) { l1 = acc[e]; i1 = e; }
        float w0 = 1.0f / (1.0f + __expf((float)(l1 - l0)));
        float w1 = 1.0f - w0;
        int p0 = atomicAdd(&counts[i0], 1);
        int p1 = atomicAdd(&counts[i1], 1);
        perm[i0 * CAP + p0] = t * 2;
        perm[i1 * CAP + p1] = t * 2 + 1;
        int q0 = atomicAdd(&counts[16 + i0 * 2], 1);      // slot0 -> even group
        int q1 = atomicAdd(&counts[16 + i1 * 2 + 1], 1);  // slot1 -> odd group
        pperm[(i0 * 2) * CAP + q0]     = t * 2;
        pperm[(i1 * 2 + 1) * CAP + q1] = t * 2 + 1;
        rw[t * 2]     = w0;
        rw[t * 2 + 1] = w1;
    }
}

// ---------------- grouped GEMM, 128x128 tile, BK=32, fp16 MFMA 16x16x32 ----------------
// m97 structure: global_load_lds staging into linear LDS, 2 barriers per K-step.
// DOWN=false: group z = expert. A = xh[token][HDIM] gathered, B = wgu[e][896][HDIM],
//             C -> fp16 stores to gu.
// DOWN=true : group gi = z*2+gsel (parity list). A = h[row][448] gathered,
//             B = d16[hdim][7168] (e-slice). ACCUM=false: out[..] = v (store pass);
//             ACCUM=true: out[..] += v (non-atomic; sole writer, stream-ordered).
template <int KTOT, bool DOWN, bool ACCUM>
__global__ __launch_bounds__(256, 3) void k_gemm(const _Float16* __restrict__ A,
                                                 const _Float16* __restrict__ B,
                                                 const int* __restrict__ counts,
                                                 const int* __restrict__ perm,
                                                 _Float16* __restrict__ gu_out,
                                                 float* __restrict__ out,
                                                 int gsel) {
    int z  = blockIdx.z;
    int gi = DOWN ? (z * 2 + gsel) : z;       // index into counts/perm lists
    int e  = z;                               // expert (z in [0,16) both ways)
    int nt = blockIdx.x;
    int cnt = counts[gi];
    __shared__ __align__(16) _Float16 As[128 * 32];   // linear: gld_lds needs contiguous dest
    __shared__ __align__(16) _Float16 Bs[128 * 32];
    __shared__ int perm_s[128];
    int tid  = threadIdx.x;
    int lane = tid & 63, wave = tid >> 6;
    int wm = wave >> 1, wn = wave & 1;        // 2x2 waves, each 64x64
    int lm = lane & 15, lq = lane >> 4;

    // staging geometry: wave w covers rows [w*16, +16) and [64+w*16, +16)
    // lane l -> row offset l>>2, 16B chunk (l&3) within the 64B row
    int rrow = lane >> 2;
    int cseg = (lane & 3) * 8;                // halves
    int row0 = wave * 16 + rrow;              // rows 0..63
    int row1 = 64 + wave * 16 + rrow;         // rows 64..127
    _Float16* As0 = &As[(wave * 16) * 32];    // wave-uniform LDS bases
    _Float16* As1 = &As[(64 + wave * 16) * 32];
    _Float16* Bs0 = &Bs[(wave * 16) * 32];
    _Float16* Bs1 = &Bs[(64 + wave * 16) * 32];

    // B row pointers depend only on (e, nt) — hoist out of the mt loop
    const _Float16 *b0, *b1;
    if (DOWN) {
        b0 = B + (int64_t)(nt * 128 + row0) * (NE * INTER) + e * INTER + cseg;
        b1 = B + (int64_t)(nt * 128 + row1) * (NE * INTER) + e * INTER + cseg;
    } else {
        b0 = B + ((int64_t)e * NGU + nt * 128 + row0) * HDIM + cseg;
        b1 = B + ((int64_t)e * NGU + nt * 128 + row1) * HDIM + cseg;
    }

    for (int mt = blockIdx.y; mt * 128 < cnt; mt += gridDim.y) {
        __syncthreads();                      // protect perm_s vs previous epilogue
        if (tid < 128) {
            int r = mt * 128 + tid;
            perm_s[tid] = (r < cnt) ? perm[gi * CAP + r] : -1;
        }
        __syncthreads();
        int pr0 = perm_s[row0], pr1 = perm_s[row1];
        const _Float16 *a0, *a1;
        if (DOWN) {
            a0 = A + (pr0 < 0 ? 0 : (int64_t)pr0 * INTER) + cseg;
            a1 = A + (pr1 < 0 ? 0 : (int64_t)pr1 * INTER) + cseg;
        } else {
            a0 = A + (pr0 < 0 ? 0 : (int64_t)(pr0 >> 1) * HDIM) + cseg;
            a1 = A + (pr1 < 0 ? 0 : (int64_t)(pr1 >> 1) * HDIM) + cseg;
        }
        const _Float16 *bb0 = b0, *bb1 = b1;

        f32x4 acc[4][4];
#pragma unroll
        for (int i = 0; i < 4; i++)
#pragma unroll
            for (int j = 0; j < 4; j++) acc[i][j] = (f32x4){0.f, 0.f, 0.f, 0.f};

#pragma unroll 1
        for (int kt = 0; kt < KTOT; kt += 32) {
            gld16(a0,  As0);  gld16(a1,  As1);
            gld16(bb0, Bs0);  gld16(bb1, Bs1);
            a0 += 32; a1 += 32; bb0 += 32; bb1 += 32;
            __syncthreads();                  // vmcnt(0) drain -> tiles resident
            half8 af[4], bfr[4];
#pragma unroll
            for (int mi = 0; mi < 4; mi++)
                af[mi] = *reinterpret_cast<const half8*>(&As[(wm * 64 + mi * 16 + lm) * 32 + lq * 8]);
#pragma unroll
            for (int ni = 0; ni < 4; ni++)
                bfr[ni] = *reinterpret_cast<const half8*>(&Bs[(wn * 64 + ni * 16 + lm) * 32 + lq * 8]);
#pragma unroll
            for (int mi = 0; mi < 4; mi++)
#pragma unroll
                for (int ni = 0; ni < 4; ni++)
                    acc[mi][ni] = __builtin_amdgcn_mfma_f32_16x16x32_f16(af[mi], bfr[ni], acc[mi][ni], 0, 0, 0);
            __syncthreads();                  // all reads done before next stage overwrites
        }
        // epilogue: C/D layout col=lane&15, row=(lane>>4)*4+reg  [m89/m91 verified]
#pragma unroll
        for (int mi = 0; mi < 4; mi++) {
#pragma unroll
            for (int r = 0; r < 4; r++) {
                int row = wm * 64 + mi * 16 + lq * 4 + r;
                int g = perm_s[row];
                if (g < 0) continue;
#pragma unroll
                for (int ni = 0; ni < 4; ni++) {
                    int col = nt * 128 + wn * 64 + ni * 16 + lm;
                    float v = acc[mi][ni][r];
                    if (DOWN) {
                        int64_t o = (int64_t)(g >> 1) * HDIM + col;
                        if (ACCUM) out[o] += v;   // sole writer; even-pass done (stream order)
                        else       out[o] = v;    // covers every token row exactly once
                    } else {
                        gu_out[(int64_t)g * NGU + col] = (_Float16)v;
                    }
                }
            }
        }
    }
}

// ---------------- swiglu + routing-weight fold ----------------
__global__ __launch_bounds__(256) void k_swiglu(const _Float16* __restrict__ gu,
                                                const float* __restrict__ rw,
                                                _Float16* __restrict__ h) {
    int64_t id  = (int64_t)blockIdx.x * 256 + threadIdx.x;   // ROWS*448/8 threads
    int64_t row = id / 56;
    int64_t j   = (id - row * 56) * 8;
    float w = rw[row];
    half8 gv = *reinterpret_cast<const half8*>(gu + row * NGU + j);
    half8 uv = *reinterpret_cast<const half8*>(gu + row * NGU + 448 + j);
    half8 o;
#pragma unroll
    for (int i = 0; i < 8; i++) {
        float g = (float)gv[i];
        float u = (float)uv[i];
        float s = g / (1.0f + __expf(-g));
        o[i] = (_Float16)(s * u * w);
    }
    *reinterpret_cast<half8*>(h + row * INTER + j) = o;
}

// ---------------- launch ----------------
extern "C" void kernel_launch(void* const* d_in, const int* in_sizes, int n_in,
                              void* d_out, int out_size, void* d_ws, size_t ws_size,
                              hipStream_t stream) {
    (void)in_sizes; (void)n_in; (void)ws_size; (void)out_size;
    const float* hid    = (const float*)d_in[0];
    const float* gate_w = (const float*)d_in[1];
    const float* u      = (const float*)d_in[2];
    const float* g      = (const float*)d_in[3];
    const float* d      = (const float*)d_in[4];
    float* out = (float*)d_out;

    // ws layout (bytes): ~231 MB total. d16 ALIASES wgu (wgu dead after gate/up
    // GEMM; convert_flat runs after it in-stream).
    char* w = (char*)d_ws;
    _Float16* xh    = (_Float16*)(w);                 //  67,108,864  x fp16 [8192][4096]
    _Float16* wgu   = (_Float16*)(w + 67108864);      // 117,440,512  [16][896][4096]
    _Float16* d16   = (_Float16*)(w + 67108864);      //  58,720,256  [4096][7168] (alias)
    _Float16* gu    = (_Float16*)(w + 184549376);     //  29,360,128  [16384][896]
    _Float16* hbuf  = (_Float16*)(w + 213909504);     //  14,680,064  [16384][448]
    int*      perm  = (int*)     (w + 228589568);     //     524,288  [16][8192] combined
    int*      pperm = (int*)     (w + 229113856);     //   1,048,576  [32][8192] parity
    float*    rw    = (float*)   (w + 230162432);     //      65,536  [16384]
    int*      cnts  = (int*)     (w + 230227968);     //         256  [48 used]

    hipMemsetAsync(cnts, 0, 256, stream);             // out NOT memset: store-pass covers it

    k_convert_gu<<<14336, 256, 0, stream>>>(g, wgu, 0);      // gate rows -> cols [0,448)
    k_convert_gu<<<14336, 256, 0, stream>>>(u, wgu, 448);    // up rows   -> cols [448,896)
    k_router<<<BS, 64, 0, stream>>>(hid, gate_w, xh, cnts, perm, pperm, rw);
    k_gemm<HDIM, false, false><<<dim3(7, 16, NE), 256, 0, stream>>>(xh, wgu, cnts, perm, gu, out, 0);
    k_convert_flat<<<14336, 256, 0, stream>>>(d, d16);       // overwrites wgu (dead)
    k_swiglu<<<3584, 256, 0, stream>>>(gu, rw, hbuf);
    // down: parity-split, no atomics. even pass stores (full coverage), odd pass adds.
    k_gemm<INTER, true, false><<<dim3(32, 8, NE), 256, 0, stream>>>(hbuf, d16, cnts + 16, pperm, nullptr, out, 0);
    k_gemm<INTER, true, true ><<<dim3(32, 8, NE), 256, 0, stream>>>(hbuf, d16, cnts + 16, pperm, nullptr, out, 1);
}